// Round 9
// baseline (541.060 us; speedup 1.0000x reference)
//
#include <hip/hip_runtime.h>

#define D_    784
#define ROWS  8               // rows per block; feature = 8 contiguous dwords
#define NCLS  10
#define BLOCK 832             // 13 waves; one thread per feature (48 idle)
#define NB    (65536 / ROWS)  // 8192 blocks
#define HSTR  8               // dword stride per feature (R7's proven layout)

// tanh-approx GELU (|err| vs exact erf-GELU ~5e-4)
__device__ __forceinline__ float gelu_f(float x) {
    float x2    = x * x;
    float inner = fmaf(0.044715f * x, x2, x);
    float e     = exp2f(2.3022082f * inner);          // 2*sqrt(2/pi)*log2(e)
    float r     = __builtin_amdgcn_rcpf(e + 1.0f);
    return fmaf(-x, r, x);                            // x*e/(e+1)
}

__device__ __forceinline__ void fma4(float4& a, const float4& h4, float wk) {
    a.x = fmaf(h4.x, wk, a.x);
    a.y = fmaf(h4.y, wk, a.y);
    a.z = fmaf(h4.z, wk, a.z);
    a.w = fmaf(h4.w, wk, a.w);
}

// One thread = one feature (all 8 rows), single shot, no loops.
// Per 2 gathers: int2+float2 load, 4 ds_read_b128, 16 fma. In-flight ~45 regs.
template <int K>
__device__ __forceinline__ void layer_fn(const float* __restrict__ src,
                                         float* __restrict__ dst,
                                         const int* __restrict__ idx,
                                         const float* __restrict__ w,
                                         const float* __restrict__ bias,
                                         int tid) {
    if (tid < D_) {
        float bv = bias[tid];
        float4 aL = make_float4(bv, bv, bv, bv);
        float4 aH = make_float4(bv, bv, bv, bv);
#pragma unroll
        for (int k2 = 0; k2 < K / 2; ++k2) {
            int2   j  = *(const int2*)(idx + tid * K + k2 * 2);
            float2 wv = *(const float2*)(w + tid * K + k2 * 2);
            const float* p0 = src + j.x * HSTR;
            const float* p1 = src + j.y * HSTR;
            float4 a0 = *(const float4*)(p0);
            float4 a1 = *(const float4*)(p0 + 4);
            float4 b0 = *(const float4*)(p1);
            float4 b1 = *(const float4*)(p1 + 4);
            fma4(aL, a0, wv.x);
            fma4(aH, a1, wv.x);
            fma4(aL, b0, wv.y);
            fma4(aH, b1, wv.y);
        }
        float* db = dst + tid * HSTR;
        *(float4*)(db)     = make_float4(gelu_f(aL.x), gelu_f(aL.y),
                                         gelu_f(aL.z), gelu_f(aL.w));
        *(float4*)(db + 4) = make_float4(gelu_f(aH.x), gelu_f(aH.y),
                                         gelu_f(aH.z), gelu_f(aH.w));
    }
    __syncthreads();
}

__global__ __launch_bounds__(BLOCK, 4)   // VGPR cap 256/4 = 64 -> 32-wave class
void circnn_kernel(const float* __restrict__ x,
                   const int* __restrict__ idx1, const float* __restrict__ w1, const float* __restrict__ b1,
                   const int* __restrict__ idx2, const float* __restrict__ w2, const float* __restrict__ b2,
                   const int* __restrict__ idx3, const float* __restrict__ w3, const float* __restrict__ b3,
                   const float* __restrict__ fcw, const float* __restrict__ fcb,
                   float* __restrict__ out) {
    __shared__ __align__(16) float bufA[D_ * HSTR];   // 25,088 B: x, h2; FC partials
    __shared__ __align__(16) float bufB[D_ * HSTR];   // 25,088 B: h1, h3
    __shared__ float logits[ROWS * NCLS];             // 320 B

    const int tid  = threadIdx.x;
    const int row0 = blockIdx.x * ROWS;

    // ---- Stage x -> bufA: 8 lane-coalesced strided b32 reads, 2 b128 writes.
    if (tid < D_) {
        const float* xb = x + (size_t)row0 * D_ + tid;
        float4 v0, v1;
        v0.x = xb[0 * D_]; v0.y = xb[1 * D_];
        v0.z = xb[2 * D_]; v0.w = xb[3 * D_];
        v1.x = xb[4 * D_]; v1.y = xb[5 * D_];
        v1.z = xb[6 * D_]; v1.w = xb[7 * D_];
        float* db = bufA + tid * HSTR;
        *(float4*)(db)     = v0;
        *(float4*)(db + 4) = v1;
    }
    __syncthreads();

    // ---- Three sparse layers, ping-pong: A->B->A->B, one feature per thread
    layer_fn<2>(bufA, bufB, idx1, w1, b1, tid);
    layer_fn<4>(bufB, bufA, idx2, w2, b2, tid);
    layer_fn<8>(bufA, bufB, idx3, w3, b3, tid);

    // ---- FC phase A: 128 threads, partials into bufA (free). No shuffles.
    float4* part4 = (float4*)bufA;    // layout [(jj*2+qq)*NCLS + c], 10,240 B
    if (tid < 128) {
        const int jj = tid >> 1;      // 0..63
        const int qq = tid & 1;       // row quad
        float4 facc[NCLS];
#pragma unroll
        for (int c = 0; c < NCLS; ++c) facc[c] = make_float4(0.f, 0.f, 0.f, 0.f);
#pragma unroll 1
        for (int i = 0; i < 13; ++i) {
            int n = jj + 64 * i;
            if (n < D_) {
                float4 hv = *(const float4*)(bufB + n * HSTR + qq * 4);
#pragma unroll
                for (int c = 0; c < NCLS; ++c)
                    fma4(facc[c], hv, fcw[c * D_ + n]);
            }
        }
#pragma unroll
        for (int c = 0; c < NCLS; ++c)
            part4[(jj * 2 + qq) * NCLS + c] = facc[c];
    }
    __syncthreads();

    // ---- FC phase B: 80 threads (r, c) sum 64 partials -> logits
    if (tid < ROWS * NCLS) {
        int r = tid / NCLS, c = tid - r * NCLS;
        int qq = r >> 2, comp = r & 3;
        const float* pf = (const float*)part4;
        float s = fcb[c];
#pragma unroll 4
        for (int jj = 0; jj < 64; ++jj)
            s += pf[((jj * 2 + qq) * NCLS + c) * 4 + comp];
        logits[tid] = s;
    }
    __syncthreads();

    // ---- softmax (redundant per-(r,c) thread), coalesced 80-float store
    if (tid < ROWS * NCLS) {
        int r = tid / NCLS;
        const float* lg = logits + r * NCLS;
        float m = lg[0];
#pragma unroll
        for (int c = 1; c < NCLS; ++c) m = fmaxf(m, lg[c]);
        float s = 0.f;
#pragma unroll
        for (int c = 0; c < NCLS; ++c) s += __expf(lg[c] - m);
        out[(size_t)row0 * NCLS + tid] = __expf(logits[tid] - m) / s;
    }
}

extern "C" void kernel_launch(void* const* d_in, const int* in_sizes, int n_in,
                              void* d_out, int out_size, void* d_ws, size_t ws_size,
                              hipStream_t stream) {
    const float* x    = (const float*)d_in[0];
    const int*   idx1 = (const int*)d_in[1];
    const float* w1   = (const float*)d_in[2];
    const float* b1   = (const float*)d_in[3];
    const int*   idx2 = (const int*)d_in[4];
    const float* w2   = (const float*)d_in[5];
    const float* b2   = (const float*)d_in[6];
    const int*   idx3 = (const int*)d_in[7];
    const float* w3   = (const float*)d_in[8];
    const float* b3   = (const float*)d_in[9];
    const float* fcw  = (const float*)d_in[10];
    const float* fcb  = (const float*)d_in[11];
    float* out = (float*)d_out;

    circnn_kernel<<<dim3(NB), dim3(BLOCK), 0, stream>>>(
        x, idx1, w1, b1, idx2, w2, b2, idx3, w3, b3, fcw, fcb, out);
}